// Round 5
// baseline (237.703 us; speedup 1.0000x reference)
//
#include <hip/hip_runtime.h>
#include <hip/hip_bf16.h>

typedef __bf16 bf16x8 __attribute__((ext_vector_type(8)));
typedef __bf16 bf16x4 __attribute__((ext_vector_type(4)));
typedef float  f32x16 __attribute__((ext_vector_type(16)));

#define GPTR(p) ((__attribute__((address_space(1))) void*)(p))
#define LPTR(p) ((__attribute__((address_space(3))) void*)(p))

// ---------------------------------------------------------------------------
// D1: cvt F_w (512) | transpose-cvt G_w (256) | gemv b2 = F_w@G_b + F_b (1024)
// (verbatim round-3 proven)
// ---------------------------------------------------------------------------
__global__ __launch_bounds__(256) void pre_kernel(
    const float* __restrict__ Fw, __bf16* __restrict__ f_bf,
    const float* __restrict__ Gw, __bf16* __restrict__ gt_bf,
    const float* __restrict__ Gb, const float* __restrict__ Fb,
    float* __restrict__ b2, int H) {
    __shared__ float tile[64][65];
    const int blk = blockIdx.x;
    const int t = threadIdx.x;

    if (blk < 512) {                       // cvt F_w
        long i = ((long)blk * 256 + t) * 8;
        float4 a = *reinterpret_cast<const float4*>(Fw + i);
        float4 c = *reinterpret_cast<const float4*>(Fw + i + 4);
        bf16x8 o;
        o[0] = (__bf16)a.x; o[1] = (__bf16)a.y; o[2] = (__bf16)a.z; o[3] = (__bf16)a.w;
        o[4] = (__bf16)c.x; o[5] = (__bf16)c.y; o[6] = (__bf16)c.z; o[7] = (__bf16)c.w;
        *reinterpret_cast<bf16x8*>(f_bf + i) = o;
    } else if (blk < 768) {                // transpose-cvt G_w: gt[k][h] = G[h][k]
        const int id = blk - 512;
        const int bx = (id & 15) * 64;
        const int by = (id >> 4) * 64;
        const int tr = t >> 4;
        const int tc = (t & 15) * 4;
#pragma unroll
        for (int i = 0; i < 4; i++) {
            float4 v = *reinterpret_cast<const float4*>(&Gw[(size_t)(by + tr + i * 16) * H + bx + tc]);
            tile[tr + i * 16][tc + 0] = v.x;
            tile[tr + i * 16][tc + 1] = v.y;
            tile[tr + i * 16][tc + 2] = v.z;
            tile[tr + i * 16][tc + 3] = v.w;
        }
        __syncthreads();
        const int wr = t >> 2;
        const int wc = (t & 3) * 16;
        bf16x8 o0, o1;
#pragma unroll
        for (int j = 0; j < 8; j++) o0[j] = (__bf16)tile[wc + j][wr];
#pragma unroll
        for (int j = 0; j < 8; j++) o1[j] = (__bf16)tile[wc + 8 + j][wr];
        *reinterpret_cast<bf16x8*>(&gt_bf[(size_t)(bx + wr) * H + by + wc]) = o0;
        *reinterpret_cast<bf16x8*>(&gt_bf[(size_t)(bx + wr) * H + by + wc + 8]) = o1;
    } else {                               // gemv b2[o] = Fw[o,:]·Gb + Fb[o]
        const int o = blk - 768;
        float s = 0.f;
        for (int h = t; h < H; h += 256) s += Fw[(size_t)o * H + h] * Gb[h];
#pragma unroll
        for (int off = 32; off > 0; off >>= 1) s += __shfl_xor(s, off);
        __shared__ float ss[4];
        if ((t & 63) == 0) ss[t >> 6] = s;
        __syncthreads();
        if (t == 0) b2[o] = ss[0] + ss[1] + ss[2] + ss[3] + Fb[o];
    }
}

// ---------------------------------------------------------------------------
// GEMM0 standalone (was mid if-branch): Wm[o][k] = sum_h F[o][h] * Gt[k][h]
// 256 blocks, 64x64 tile, 16 KB LDS.
// ---------------------------------------------------------------------------
__global__ __launch_bounds__(256) void gemm0_kernel(
    const __bf16* __restrict__ f_bf, const __bf16* __restrict__ gt_bf,
    __bf16* __restrict__ Wm, int H) {
    __shared__ __align__(16) __bf16 As[64 * 64];
    __shared__ __align__(16) __bf16 Bs[64 * 64];
    const int blk = blockIdx.x;
    const int t = threadIdx.x;
    const int lane = t & 63;
    const int wave = t >> 6;
    const int lane31 = lane & 31;
    const int hi = lane >> 5;
    const int wm = (wave >> 1) * 32;
    const int wn = (wave & 1) * 32;
    const int bm = (blk >> 4) * 64;
    const int bn = (blk & 15) * 64;

    const int rsub = lane >> 3;
    const int csub = lane & 7;
    const int lchunk = csub ^ rsub;
    const __bf16* ga0 = f_bf + (size_t)(bm + wave * 16 + rsub) * H + lchunk * 8;
    const __bf16* gb0 = gt_bf + (size_t)(bn + wave * 16 + rsub) * H + lchunk * 8;

    f32x16 acc = (f32x16)(0.f);
    for (int kt = 0; kt < H; kt += 64) {
        __syncthreads();
#pragma unroll
        for (int c = 0; c < 2; c++)
            __builtin_amdgcn_global_load_lds(GPTR(ga0 + (size_t)(c * 8) * H + kt),
                                             LPTR(&As[(wave * 16 + c * 8) * 64]), 16, 0, 0);
#pragma unroll
        for (int c = 0; c < 2; c++)
            __builtin_amdgcn_global_load_lds(GPTR(gb0 + (size_t)(c * 8) * H + kt),
                                             LPTR(&Bs[(wave * 16 + c * 8) * 64]), 16, 0, 0);
        __syncthreads();
#pragma unroll
        for (int s = 0; s < 4; s++) {
            const int ra = wm + lane31;
            const int rb = wn + lane31;
            bf16x8 af = *reinterpret_cast<const bf16x8*>(
                &As[ra * 64 + (((2 * s + hi) ^ (ra & 7)) << 3)]);
            bf16x8 bfr = *reinterpret_cast<const bf16x8*>(
                &Bs[rb * 64 + (((2 * s + hi) ^ (rb & 7)) << 3)]);
            acc = __builtin_amdgcn_mfma_f32_32x32x16_bf16(af, bfr, acc, 0, 0, 0);
        }
    }
    const int cm = bm + wm;
    const int cn = bn + wn + lane31;
#pragma unroll
    for (int rq = 0; rq < 4; rq++) {
        const int rbase = rq * 8 + 4 * hi;
#pragma unroll
        for (int rr = 0; rr < 4; rr++)
            Wm[(size_t)(cm + rbase + rr) * H + cn] = (__bf16)acc[rq * 4 + rr];
    }
}

// ---------------------------------------------------------------------------
// Softmax standalone (was mid else-branch): block-per-row, 32 B LDS only ->
// occupancy unlocked (8 blocks/CU possible vs 2-4 when union'd with GEMM LDS).
// ---------------------------------------------------------------------------
__global__ __launch_bounds__(256) void softmax_kernel(
    const float* __restrict__ R, const float* __restrict__ mask,
    __bf16* __restrict__ P, int S) {
    __shared__ float red[8];
    const int id = blockIdx.x;             // 0..8191
    const int t = threadIdx.x;
    const int b = id >> 11;
    const int q = id & 2047;
    const int lane = t & 63, wave = t >> 6;
    const float* rrow = R + (size_t)q * S;
    const float* mrow = mask + ((size_t)b * S + q) * (size_t)S;
    __bf16* prow = P + ((size_t)b * S + q) * (size_t)S;

    float v[8];
#pragma unroll
    for (int i = 0; i < 2; i++) {
        float4 r4 = *reinterpret_cast<const float4*>(rrow + t * 8 + i * 4);
        float4 m4 = *reinterpret_cast<const float4*>(mrow + t * 8 + i * 4);
        v[i * 4 + 0] = r4.x + m4.x;
        v[i * 4 + 1] = r4.y + m4.y;
        v[i * 4 + 2] = r4.z + m4.z;
        v[i * 4 + 3] = r4.w + m4.w;
    }
    float mx = v[0];
#pragma unroll
    for (int i = 1; i < 8; i++) mx = fmaxf(mx, v[i]);
#pragma unroll
    for (int off = 32; off > 0; off >>= 1) mx = fmaxf(mx, __shfl_xor(mx, off));
    if (lane == 0) red[wave] = mx;
    __syncthreads();
    mx = fmaxf(fmaxf(red[0], red[1]), fmaxf(red[2], red[3]));
    float sum = 0.f;
#pragma unroll
    for (int i = 0; i < 8; i++) { v[i] = __expf(v[i] - mx); sum += v[i]; }
#pragma unroll
    for (int off = 32; off > 0; off >>= 1) sum += __shfl_xor(sum, off);
    if (lane == 0) red[4 + wave] = sum;
    __syncthreads();
    sum = red[4] + red[5] + red[6] + red[7];
    const float inv = 1.0f / sum;
    bf16x8 o;
#pragma unroll
    for (int i = 0; i < 8; i++) o[i] = (__bf16)(v[i] * inv);
    *reinterpret_cast<bf16x8*>(prow + t * 8) = o;
}

// ---------------------------------------------------------------------------
// Y-GEMM (verbatim round-3 proven): Yt[b][h][s] = sum_g W[h][g]*hidden[b][s][g]
// ---------------------------------------------------------------------------
__global__ __launch_bounds__(256) void gemm_wy_kernel(
    const __bf16* __restrict__ Wm, const float* __restrict__ hidden,
    __bf16* __restrict__ Yt) {
    constexpr int H = 1024, S = 2048, K = 1024;
    const int t = threadIdx.x;
    const int lane = t & 63;
    const int wave = t >> 6;
    const int lane31 = lane & 31;
    const int hi = lane >> 5;
    const int wm = (wave >> 1) * 64;
    const int wn = (wave & 1) * 64;
    const int id = blockIdx.x;               // 512 = 8 m-tiles x 64 n-tiles
    const int xcd = id & 7;
    const int slot = id >> 3;
    const int bm = (slot & 7) * 128;         // h tile
    const int bn = (xcd * 8 + (slot >> 3)) * 128;  // flat-s tile

    __shared__ __align__(16) __bf16 smem[32768];   // 2 x (As 16KB | Bs 16KB)

    const int rsub = lane >> 3;
    const int csub = lane & 7;
    const int lchunk = csub ^ rsub;
    const __bf16* ga0 = Wm + (size_t)(bm + wave * 32 + rsub) * K + lchunk * 8;

    auto stageA = [&](int p, int kt) {
#pragma unroll
        for (int c = 0; c < 4; c++)
            __builtin_amdgcn_global_load_lds(GPTR(ga0 + (size_t)(c * 8) * K + kt),
                LPTR(&smem[p * 16384 + (wave * 32 + c * 8) * 64]), 16, 0, 0);
    };

    const int q4 = t & 15;
    const int rr = t >> 4;
    const int cg = q4 >> 1;
    const int h8 = (q4 & 1) * 4;
    float4 br[8];
    auto loadB = [&](int kt) {
#pragma unroll
        for (int i = 0; i < 8; i++)
            br[i] = *reinterpret_cast<const float4*>(
                hidden + (size_t)(bn + rr + i * 16) * K + kt + q4 * 4);
    };
    auto writeB = [&](int p) {
#pragma unroll
        for (int i = 0; i < 8; i++) {
            const int r = rr + i * 16;
            bf16x4 o;
            o[0] = (__bf16)br[i].x; o[1] = (__bf16)br[i].y;
            o[2] = (__bf16)br[i].z; o[3] = (__bf16)br[i].w;
            *reinterpret_cast<bf16x4*>(
                &smem[p * 16384 + 8192 + r * 64 + ((cg ^ (r & 7)) << 3) + h8]) = o;
        }
    };

    f32x16 acc[2][2];
#pragma unroll
    for (int i = 0; i < 2; i++)
#pragma unroll
        for (int j = 0; j < 2; j++) acc[i][j] = (f32x16)(0.f);

    loadB(0);
    stageA(0, 0);
    writeB(0);
    __syncthreads();
    int p = 0;
    for (int kt = 0; kt < K; kt += 64) {
        const bool pre = kt + 64 < K;
        if (pre) { loadB(kt + 64); stageA(p ^ 1, kt + 64); }
        const __bf16* As = smem + p * 16384;
        const __bf16* Bs = smem + p * 16384 + 8192;
#pragma unroll
        for (int s = 0; s < 4; s++) {
            bf16x8 af[2], bfr[2];
#pragma unroll
            for (int mi = 0; mi < 2; mi++) {
                const int r = wm + mi * 32 + lane31;
                af[mi] = *reinterpret_cast<const bf16x8*>(
                    &As[r * 64 + (((2 * s + hi) ^ (r & 7)) << 3)]);
            }
#pragma unroll
            for (int ni = 0; ni < 2; ni++) {
                const int r = wn + ni * 32 + lane31;
                bfr[ni] = *reinterpret_cast<const bf16x8*>(
                    &Bs[r * 64 + (((2 * s + hi) ^ (r & 7)) << 3)]);
            }
#pragma unroll
            for (int mi = 0; mi < 2; mi++)
#pragma unroll
                for (int ni = 0; ni < 2; ni++)
                    acc[mi][ni] = __builtin_amdgcn_mfma_f32_32x32x16_bf16(af[mi], bfr[ni], acc[mi][ni], 0, 0, 0);
        }
        if (pre) writeB(p ^ 1);
        __syncthreads();
        p ^= 1;
    }

#pragma unroll
    for (int mi = 0; mi < 2; mi++)
#pragma unroll
        for (int ni = 0; ni < 2; ni++) {
            const int cm = bm + wm + mi * 32;
            const int cnf = bn + wn + ni * 32 + lane31;
            __bf16* Cb = Yt + (size_t)(cnf >> 11) * H * S + (cnf & 2047);
#pragma unroll
            for (int rq = 0; rq < 4; rq++) {
                const int rbase = rq * 8 + 4 * hi;
#pragma unroll
                for (int rrq = 0; rrq < 4; rrq++)
                    Cb[(size_t)(cm + rbase + rrq) * S] = (__bf16)acc[mi][ni][rq * 4 + rrq];
            }
        }
}

// ---------------------------------------------------------------------------
// Final NT GEMM (verbatim round-3 proven):
//   out[b][q][o] = sum_s P[b][q][s] * Yt[b][o][s] + b2[o]   (fp32 out)
// ---------------------------------------------------------------------------
template <bool CFLOAT, bool BIAS>
__global__ __launch_bounds__(256) void gemm_nt_kernel(
    const __bf16* __restrict__ A, const __bf16* __restrict__ B,
    const float* __restrict__ bias, void* __restrict__ Cv,
    int K, int lda, int ldb, int ldc,
    long strideA, long strideB, long strideC) {
    const int t = threadIdx.x;
    const int lane = t & 63;
    const int wave = t >> 6;
    const int lane31 = lane & 31;
    const int hi = lane >> 5;
    const int wm = (wave >> 1) * 64;
    const int wn = (wave & 1) * 64;
    const int id = blockIdx.x;
    const int xcd = id & 7;
    const int slot = id >> 3;
    const int bz = xcd >> 1;
    const int bm = ((xcd & 1) * 8 + (slot >> 3)) * 128;
    const int bn = (slot & 7) * 128;

    A += (size_t)bz * strideA;
    B += (size_t)bz * strideB;

    __shared__ __align__(16) __bf16 smem[32768];   // 64 KB

    const int rsub = lane >> 3;
    const int csub = lane & 7;
    const int lchunk = csub ^ rsub;
    const __bf16* ga0 = A + (size_t)(bm + wave * 32 + rsub) * lda + lchunk * 8;
    const __bf16* gb0 = B + (size_t)(bn + wave * 32 + rsub) * ldb + lchunk * 8;

    auto stage = [&](int p, int kt) {
        __bf16* As_ = smem + p * 16384;
        __bf16* Bs_ = smem + p * 16384 + 8192;
#pragma unroll
        for (int c = 0; c < 4; c++)
            __builtin_amdgcn_global_load_lds(GPTR(ga0 + (size_t)(c * 8) * lda + kt),
                                             LPTR(&As_[(wave * 32 + c * 8) * 64]), 16, 0, 0);
#pragma unroll
        for (int c = 0; c < 4; c++)
            __builtin_amdgcn_global_load_lds(GPTR(gb0 + (size_t)(c * 8) * ldb + kt),
                                             LPTR(&Bs_[(wave * 32 + c * 8) * 64]), 16, 0, 0);
    };

    f32x16 acc[2][2];
#pragma unroll
    for (int i = 0; i < 2; i++)
#pragma unroll
        for (int j = 0; j < 2; j++) acc[i][j] = (f32x16)(0.f);

    stage(0, 0);
    __syncthreads();
    int p = 0;
    for (int kt = 0; kt < K; kt += 64) {
        if (kt + 64 < K) stage(p ^ 1, kt + 64);
        const __bf16* As = smem + p * 16384;
        const __bf16* Bs = smem + p * 16384 + 8192;
#pragma unroll
        for (int s = 0; s < 4; s++) {
            bf16x8 af[2], bfr[2];
#pragma unroll
            for (int mi = 0; mi < 2; mi++) {
                const int r = wm + mi * 32 + lane31;
                af[mi] = *reinterpret_cast<const bf16x8*>(
                    &As[r * 64 + (((2 * s + hi) ^ (r & 7)) << 3)]);
            }
#pragma unroll
            for (int ni = 0; ni < 2; ni++) {
                const int r = wn + ni * 32 + lane31;
                bfr[ni] = *reinterpret_cast<const bf16x8*>(
                    &Bs[r * 64 + (((2 * s + hi) ^ (r & 7)) << 3)]);
            }
#pragma unroll
            for (int mi = 0; mi < 2; mi++)
#pragma unroll
                for (int ni = 0; ni < 2; ni++)
                    acc[mi][ni] = __builtin_amdgcn_mfma_f32_32x32x16_bf16(af[mi], bfr[ni], acc[mi][ni], 0, 0, 0);
        }
        __syncthreads();
        p ^= 1;
    }

    __bf16* Cb = (__bf16*)Cv + (size_t)bz * strideC;
    float* Cf = (float*)Cv + (size_t)bz * strideC;
#pragma unroll
    for (int mi = 0; mi < 2; mi++)
#pragma unroll
        for (int ni = 0; ni < 2; ni++) {
            const int cm = bm + wm + mi * 32;
            const int cn = bn + wn + ni * 32 + lane31;
            const float bv = BIAS ? bias[cn] : 0.0f;
#pragma unroll
            for (int rq = 0; rq < 4; rq++) {
                const int rbase = rq * 8 + 4 * hi;
                if constexpr (CFLOAT) {
#pragma unroll
                    for (int rr = 0; rr < 4; rr++)
                        Cf[(size_t)(cm + rbase + rr) * ldc + cn] = acc[mi][ni][rq * 4 + rr] + bv;
                } else {
#pragma unroll
                    for (int rr = 0; rr < 4; rr++)
                        Cb[(size_t)(cm + rbase + rr) * ldc + cn] = (__bf16)(acc[mi][ni][rq * 4 + rr] + bv);
                }
            }
        }
}

// ---------------------------------------------------------------------------
// 5-dispatch probe: round-3 chain with mid split into gemm0 + softmax.
// Work-delta ~0 vs round 3; discriminates per-launch-gap (H1) vs fixed-floor
// (H2) overhead models AND surfaces per-kernel durations in the top-5.
// ---------------------------------------------------------------------------
extern "C" void kernel_launch(void* const* d_in, const int* in_sizes, int n_in,
                              void* d_out, int out_size, void* d_ws, size_t ws_size,
                              hipStream_t stream) {
    const float* hidden = (const float*)d_in[0];
    const float* mask   = (const float*)d_in[1];
    const float* R      = (const float*)d_in[2];
    const float* G_w    = (const float*)d_in[3];
    const float* G_b    = (const float*)d_in[4];
    const float* F_w    = (const float*)d_in[5];
    const float* F_b    = (const float*)d_in[6];
    float* out = (float*)d_out;

    constexpr int B = 4, S = 2048, H = 1024;
    char* ws = (char*)d_ws;
    __bf16* probs = (__bf16*)(ws);                   // 32 MB  P[b][q][s]
    __bf16* yt    = (__bf16*)(ws + (32ll << 20));    // 16 MB  Yt[b][h][s]
    __bf16* f_bf  = (__bf16*)(ws + (48ll << 20));    // 2 MB
    __bf16* gt_bf = (__bf16*)(ws + (50ll << 20));    // 2 MB
    __bf16* Wm    = (__bf16*)(ws + (52ll << 20));    // 2 MB
    float*  b2    = (float*)(ws + (54ll << 20));     // 4 KB

    pre_kernel<<<1792, 256, 0, stream>>>(F_w, f_bf, G_w, gt_bf, G_b, F_b, b2, H);

    gemm0_kernel<<<256, 256, 0, stream>>>(f_bf, gt_bf, Wm, H);

    softmax_kernel<<<8192, 256, 0, stream>>>(R, mask, probs, S);

    // Yt[b][h][s] = sum_g W[h][g] * hidden[b][s][g]
    gemm_wy_kernel<<<512, 256, 0, stream>>>(Wm, hidden, yt);

    // out[b][q][o] = sum_s P[b][q][s] * Yt[b][o][s] + b2[o]
    gemm_nt_kernel<true, true><<<512, 256, 0, stream>>>(
        probs, yt, b2, out, S, S, S, H,
        (long)S * S, (long)H * S, (long)S * H);
}

// Round 6
// 222.662 us; speedup vs baseline: 1.0676x; 1.0676x over previous
//
#include <hip/hip_runtime.h>
#include <hip/hip_bf16.h>

typedef __bf16 bf16x8 __attribute__((ext_vector_type(8)));
typedef __bf16 bf16x4 __attribute__((ext_vector_type(4)));
typedef float  f32x16 __attribute__((ext_vector_type(16)));

#define GPTR(p) ((__attribute__((address_space(1))) void*)(p))
#define LPTR(p) ((__attribute__((address_space(3))) void*)(p))

// ---------------------------------------------------------------------------
// D1: cvt F_w (0..511) | transpose-cvt G_w (512..767) | gemv b2 (768..1791)
//     | cvt hidden -> xh bf16, same [s][g] layout (1792..3839)
// ---------------------------------------------------------------------------
__global__ __launch_bounds__(256) void pre_kernel(
    const float* __restrict__ Fw, __bf16* __restrict__ f_bf,
    const float* __restrict__ Gw, __bf16* __restrict__ gt_bf,
    const float* __restrict__ Gb, const float* __restrict__ Fb,
    float* __restrict__ b2,
    const float* __restrict__ hidden, __bf16* __restrict__ xh, int H) {
    __shared__ float tile[64][65];
    const int blk = blockIdx.x;
    const int t = threadIdx.x;

    if (blk < 512) {                       // cvt F_w
        long i = ((long)blk * 256 + t) * 8;
        float4 a = *reinterpret_cast<const float4*>(Fw + i);
        float4 c = *reinterpret_cast<const float4*>(Fw + i + 4);
        bf16x8 o;
        o[0] = (__bf16)a.x; o[1] = (__bf16)a.y; o[2] = (__bf16)a.z; o[3] = (__bf16)a.w;
        o[4] = (__bf16)c.x; o[5] = (__bf16)c.y; o[6] = (__bf16)c.z; o[7] = (__bf16)c.w;
        *reinterpret_cast<bf16x8*>(f_bf + i) = o;
    } else if (blk < 768) {                // transpose-cvt G_w: gt[k][h] = G[h][k]
        const int id = blk - 512;
        const int bx = (id & 15) * 64;
        const int by = (id >> 4) * 64;
        const int tr = t >> 4;
        const int tc = (t & 15) * 4;
#pragma unroll
        for (int i = 0; i < 4; i++) {
            float4 v = *reinterpret_cast<const float4*>(&Gw[(size_t)(by + tr + i * 16) * H + bx + tc]);
            tile[tr + i * 16][tc + 0] = v.x;
            tile[tr + i * 16][tc + 1] = v.y;
            tile[tr + i * 16][tc + 2] = v.z;
            tile[tr + i * 16][tc + 3] = v.w;
        }
        __syncthreads();
        const int wr = t >> 2;
        const int wc = (t & 3) * 16;
        bf16x8 o0, o1;
#pragma unroll
        for (int j = 0; j < 8; j++) o0[j] = (__bf16)tile[wc + j][wr];
#pragma unroll
        for (int j = 0; j < 8; j++) o1[j] = (__bf16)tile[wc + 8 + j][wr];
        *reinterpret_cast<bf16x8*>(&gt_bf[(size_t)(bx + wr) * H + by + wc]) = o0;
        *reinterpret_cast<bf16x8*>(&gt_bf[(size_t)(bx + wr) * H + by + wc + 8]) = o1;
    } else if (blk < 1792) {               // gemv b2[o] = Fw[o,:]·Gb + Fb[o]
        const int o = blk - 768;
        float s = 0.f;
        for (int h = t; h < H; h += 256) s += Fw[(size_t)o * H + h] * Gb[h];
#pragma unroll
        for (int off = 32; off > 0; off >>= 1) s += __shfl_xor(s, off);
        __shared__ float ss[4];
        if ((t & 63) == 0) ss[t >> 6] = s;
        __syncthreads();
        if (t == 0) b2[o] = ss[0] + ss[1] + ss[2] + ss[3] + Fb[o];
    } else {                               // cvt hidden (8.39M elems / 2048 blocks)
        const int id = blk - 1792;
        const long base = (long)id * 4096 + (long)t * 16;
        float4 v0 = *reinterpret_cast<const float4*>(hidden + base);
        float4 v1 = *reinterpret_cast<const float4*>(hidden + base + 4);
        float4 v2 = *reinterpret_cast<const float4*>(hidden + base + 8);
        float4 v3 = *reinterpret_cast<const float4*>(hidden + base + 12);
        bf16x8 o0, o1;
        o0[0] = (__bf16)v0.x; o0[1] = (__bf16)v0.y; o0[2] = (__bf16)v0.z; o0[3] = (__bf16)v0.w;
        o0[4] = (__bf16)v1.x; o0[5] = (__bf16)v1.y; o0[6] = (__bf16)v1.z; o0[7] = (__bf16)v1.w;
        o1[0] = (__bf16)v2.x; o1[1] = (__bf16)v2.y; o1[2] = (__bf16)v2.z; o1[3] = (__bf16)v2.w;
        o1[4] = (__bf16)v3.x; o1[5] = (__bf16)v3.y; o1[6] = (__bf16)v3.z; o1[7] = (__bf16)v3.w;
        *reinterpret_cast<bf16x8*>(xh + base) = o0;
        *reinterpret_cast<bf16x8*>(xh + base + 8) = o1;
    }
}

// ---------------------------------------------------------------------------
// D2 (round-3 proven verbatim): GEMM0 W=F·Gt (0..255) | softmax (256..8447)
// ---------------------------------------------------------------------------
union MidSmem {
    struct { __bf16 a[64 * 64]; __bf16 b[64 * 64]; } g;
    float red[8];
};

__global__ __launch_bounds__(256) void mid_kernel(
    const __bf16* __restrict__ f_bf, const __bf16* __restrict__ gt_bf,
    __bf16* __restrict__ Wm,
    const float* __restrict__ R, const float* __restrict__ mask,
    __bf16* __restrict__ P, int H, int S) {
    __shared__ __align__(16) MidSmem sm;
    const int blk = blockIdx.x;
    const int t = threadIdx.x;

    if (blk < 256) {  // GEMM0 64x64 tile: Wm[o][k] = sum_h F[o][h] * Gt[k][h]
        __bf16* As = sm.g.a;
        __bf16* Bs = sm.g.b;
        const int lane = t & 63;
        const int wave = t >> 6;
        const int lane31 = lane & 31;
        const int hi = lane >> 5;
        const int wm = (wave >> 1) * 32;
        const int wn = (wave & 1) * 32;
        const int bm = (blk >> 4) * 64;
        const int bn = (blk & 15) * 64;

        const int rsub = lane >> 3;
        const int csub = lane & 7;
        const int lchunk = csub ^ rsub;
        const __bf16* ga0 = f_bf + (size_t)(bm + wave * 16 + rsub) * H + lchunk * 8;
        const __bf16* gb0 = gt_bf + (size_t)(bn + wave * 16 + rsub) * H + lchunk * 8;

        f32x16 acc = (f32x16)(0.f);
        for (int kt = 0; kt < H; kt += 64) {
            __syncthreads();
#pragma unroll
            for (int c = 0; c < 2; c++)
                __builtin_amdgcn_global_load_lds(GPTR(ga0 + (size_t)(c * 8) * H + kt),
                                                 LPTR(&As[(wave * 16 + c * 8) * 64]), 16, 0, 0);
#pragma unroll
            for (int c = 0; c < 2; c++)
                __builtin_amdgcn_global_load_lds(GPTR(gb0 + (size_t)(c * 8) * H + kt),
                                                 LPTR(&Bs[(wave * 16 + c * 8) * 64]), 16, 0, 0);
            __syncthreads();
#pragma unroll
            for (int s = 0; s < 4; s++) {
                const int ra = wm + lane31;
                const int rb = wn + lane31;
                bf16x8 af = *reinterpret_cast<const bf16x8*>(
                    &As[ra * 64 + (((2 * s + hi) ^ (ra & 7)) << 3)]);
                bf16x8 bfr = *reinterpret_cast<const bf16x8*>(
                    &Bs[rb * 64 + (((2 * s + hi) ^ (rb & 7)) << 3)]);
                acc = __builtin_amdgcn_mfma_f32_32x32x16_bf16(af, bfr, acc, 0, 0, 0);
            }
        }
        const int cm = bm + wm;
        const int cn = bn + wn + lane31;
#pragma unroll
        for (int rq = 0; rq < 4; rq++) {
            const int rbase = rq * 8 + 4 * hi;
#pragma unroll
            for (int rr = 0; rr < 4; rr++)
                Wm[(size_t)(cm + rbase + rr) * H + cn] = (__bf16)acc[rq * 4 + rr];
        }
    } else {          // softmax row (256 threads per row)
        const int id = blk - 256;          // 0..8191
        const int b = id >> 11;
        const int q = id & 2047;
        const int lane = t & 63, wave = t >> 6;
        const float* rrow = R + (size_t)q * S;
        const float* mrow = mask + ((size_t)b * S + q) * (size_t)S;
        __bf16* prow = P + ((size_t)b * S + q) * (size_t)S;

        float v[8];
#pragma unroll
        for (int i = 0; i < 2; i++) {
            float4 r4 = *reinterpret_cast<const float4*>(rrow + t * 8 + i * 4);
            float4 m4 = *reinterpret_cast<const float4*>(mrow + t * 8 + i * 4);
            v[i * 4 + 0] = r4.x + m4.x;
            v[i * 4 + 1] = r4.y + m4.y;
            v[i * 4 + 2] = r4.z + m4.z;
            v[i * 4 + 3] = r4.w + m4.w;
        }
        float mx = v[0];
#pragma unroll
        for (int i = 1; i < 8; i++) mx = fmaxf(mx, v[i]);
#pragma unroll
        for (int off = 32; off > 0; off >>= 1) mx = fmaxf(mx, __shfl_xor(mx, off));
        if (lane == 0) sm.red[wave] = mx;
        __syncthreads();
        mx = fmaxf(fmaxf(sm.red[0], sm.red[1]), fmaxf(sm.red[2], sm.red[3]));
        float sum = 0.f;
#pragma unroll
        for (int i = 0; i < 8; i++) { v[i] = __expf(v[i] - mx); sum += v[i]; }
#pragma unroll
        for (int off = 32; off > 0; off >>= 1) sum += __shfl_xor(sum, off);
        if (lane == 0) sm.red[4 + wave] = sum;
        __syncthreads();
        sum = sm.red[4] + sm.red[5] + sm.red[6] + sm.red[7];
        const float inv = 1.0f / sum;
        bf16x8 o;
#pragma unroll
        for (int i = 0; i < 8; i++) o[i] = (__bf16)(v[i] * inv);
        *reinterpret_cast<bf16x8*>(prow + t * 8) = o;
    }
}

// ---------------------------------------------------------------------------
// Y-GEMM, now pure bf16 NT with global_load_lds both operands (m97 staging):
//   C[m=h][n=s_flat] = sum_g Wm[h][g] * xh[s_flat][g];  Yt[b][h][s] = C
// 128x128 tile, BK=64, 16 K-iters, grid 512 = 8 h-tiles x 64 s-tiles.
// XCD map: id&7 -> s-group (xh panel L2-resident per XCD; Wm 2MB L2-resident).
// Epilogue: transposed write, coalesced at 64 B per half-wave (verified OK).
// ---------------------------------------------------------------------------
__global__ __launch_bounds__(256) void gemm_wy_kernel(
    const __bf16* __restrict__ Wm, const __bf16* __restrict__ xh,
    __bf16* __restrict__ Yt) {
    constexpr int H = 1024, S = 2048, K = 1024;
    const int t = threadIdx.x;
    const int lane = t & 63;
    const int wave = t >> 6;
    const int lane31 = lane & 31;
    const int hi = lane >> 5;
    const int wm = (wave >> 1) * 64;
    const int wn = (wave & 1) * 64;
    const int id = blockIdx.x;               // 512 = 8 m-tiles x 64 n-tiles
    const int xcd = id & 7;
    const int slot = id >> 3;
    const int bm = (slot & 7) * 128;         // h tile
    const int bn = (xcd * 8 + (slot >> 3)) * 128;  // flat-s tile

    __shared__ __align__(16) __bf16 smem[32768];   // 64 KB dbuf

    const int rsub = lane >> 3;
    const int csub = lane & 7;
    const int lchunk = csub ^ rsub;
    const __bf16* ga0 = Wm + (size_t)(bm + wave * 32 + rsub) * K + lchunk * 8;
    const __bf16* gb0 = xh + (size_t)(bn + wave * 32 + rsub) * K + lchunk * 8;

    auto stage = [&](int p, int kt) {
        __bf16* As_ = smem + p * 16384;
        __bf16* Bs_ = smem + p * 16384 + 8192;
#pragma unroll
        for (int c = 0; c < 4; c++)
            __builtin_amdgcn_global_load_lds(GPTR(ga0 + (size_t)(c * 8) * K + kt),
                                             LPTR(&As_[(wave * 32 + c * 8) * 64]), 16, 0, 0);
#pragma unroll
        for (int c = 0; c < 4; c++)
            __builtin_amdgcn_global_load_lds(GPTR(gb0 + (size_t)(c * 8) * K + kt),
                                             LPTR(&Bs_[(wave * 32 + c * 8) * 64]), 16, 0, 0);
    };

    f32x16 acc[2][2];
#pragma unroll
    for (int i = 0; i < 2; i++)
#pragma unroll
        for (int j = 0; j < 2; j++) acc[i][j] = (f32x16)(0.f);

    stage(0, 0);
    __syncthreads();
    int p = 0;
    for (int kt = 0; kt < K; kt += 64) {
        if (kt + 64 < K) stage(p ^ 1, kt + 64);
        const __bf16* As = smem + p * 16384;
        const __bf16* Bs = smem + p * 16384 + 8192;
#pragma unroll
        for (int s = 0; s < 4; s++) {
            bf16x8 af[2], bfr[2];
#pragma unroll
            for (int mi = 0; mi < 2; mi++) {
                const int r = wm + mi * 32 + lane31;
                af[mi] = *reinterpret_cast<const bf16x8*>(
                    &As[r * 64 + (((2 * s + hi) ^ (r & 7)) << 3)]);
            }
#pragma unroll
            for (int ni = 0; ni < 2; ni++) {
                const int r = wn + ni * 32 + lane31;
                bfr[ni] = *reinterpret_cast<const bf16x8*>(
                    &Bs[r * 64 + (((2 * s + hi) ^ (r & 7)) << 3)]);
            }
#pragma unroll
            for (int mi = 0; mi < 2; mi++)
#pragma unroll
                for (int ni = 0; ni < 2; ni++)
                    acc[mi][ni] = __builtin_amdgcn_mfma_f32_32x32x16_bf16(af[mi], bfr[ni], acc[mi][ni], 0, 0, 0);
        }
        __syncthreads();
        p ^= 1;
    }

    // Transposed epilogue: Yt[b][h][s]; lanes span s -> 64 B coalesced chunks.
#pragma unroll
    for (int mi = 0; mi < 2; mi++)
#pragma unroll
        for (int ni = 0; ni < 2; ni++) {
            const int cm = bm + wm + mi * 32;
            const int cnf = bn + wn + ni * 32 + lane31;
            __bf16* Cb = Yt + (size_t)(cnf >> 11) * H * S + (cnf & 2047);
#pragma unroll
            for (int rq = 0; rq < 4; rq++) {
                const int rbase = rq * 8 + 4 * hi;
#pragma unroll
                for (int rrq = 0; rrq < 4; rrq++)
                    Cb[(size_t)(cm + rbase + rrq) * S] = (__bf16)acc[mi][ni][rq * 4 + rrq];
            }
        }
}

// ---------------------------------------------------------------------------
// Final NT GEMM (round-3/5 proven verbatim):
//   out[b][q][o] = sum_s P[b][q][s] * Yt[b][o][s] + b2[o]   (fp32 out)
// ---------------------------------------------------------------------------
template <bool CFLOAT, bool BIAS>
__global__ __launch_bounds__(256) void gemm_nt_kernel(
    const __bf16* __restrict__ A, const __bf16* __restrict__ B,
    const float* __restrict__ bias, void* __restrict__ Cv,
    int K, int lda, int ldb, int ldc,
    long strideA, long strideB, long strideC) {
    const int t = threadIdx.x;
    const int lane = t & 63;
    const int wave = t >> 6;
    const int lane31 = lane & 31;
    const int hi = lane >> 5;
    const int wm = (wave >> 1) * 64;
    const int wn = (wave & 1) * 64;
    const int id = blockIdx.x;
    const int xcd = id & 7;
    const int slot = id >> 3;
    const int bz = xcd >> 1;
    const int bm = ((xcd & 1) * 8 + (slot >> 3)) * 128;
    const int bn = (slot & 7) * 128;

    A += (size_t)bz * strideA;
    B += (size_t)bz * strideB;

    __shared__ __align__(16) __bf16 smem[32768];   // 64 KB

    const int rsub = lane >> 3;
    const int csub = lane & 7;
    const int lchunk = csub ^ rsub;
    const __bf16* ga0 = A + (size_t)(bm + wave * 32 + rsub) * lda + lchunk * 8;
    const __bf16* gb0 = B + (size_t)(bn + wave * 32 + rsub) * ldb + lchunk * 8;

    auto stage = [&](int p, int kt) {
        __bf16* As_ = smem + p * 16384;
        __bf16* Bs_ = smem + p * 16384 + 8192;
#pragma unroll
        for (int c = 0; c < 4; c++)
            __builtin_amdgcn_global_load_lds(GPTR(ga0 + (size_t)(c * 8) * lda + kt),
                                             LPTR(&As_[(wave * 32 + c * 8) * 64]), 16, 0, 0);
#pragma unroll
        for (int c = 0; c < 4; c++)
            __builtin_amdgcn_global_load_lds(GPTR(gb0 + (size_t)(c * 8) * ldb + kt),
                                             LPTR(&Bs_[(wave * 32 + c * 8) * 64]), 16, 0, 0);
    };

    f32x16 acc[2][2];
#pragma unroll
    for (int i = 0; i < 2; i++)
#pragma unroll
        for (int j = 0; j < 2; j++) acc[i][j] = (f32x16)(0.f);

    stage(0, 0);
    __syncthreads();
    int p = 0;
    for (int kt = 0; kt < K; kt += 64) {
        if (kt + 64 < K) stage(p ^ 1, kt + 64);
        const __bf16* As = smem + p * 16384;
        const __bf16* Bs = smem + p * 16384 + 8192;
#pragma unroll
        for (int s = 0; s < 4; s++) {
            bf16x8 af[2], bfr[2];
#pragma unroll
            for (int mi = 0; mi < 2; mi++) {
                const int r = wm + mi * 32 + lane31;
                af[mi] = *reinterpret_cast<const bf16x8*>(
                    &As[r * 64 + (((2 * s + hi) ^ (r & 7)) << 3)]);
            }
#pragma unroll
            for (int ni = 0; ni < 2; ni++) {
                const int r = wn + ni * 32 + lane31;
                bfr[ni] = *reinterpret_cast<const bf16x8*>(
                    &Bs[r * 64 + (((2 * s + hi) ^ (r & 7)) << 3)]);
            }
#pragma unroll
            for (int mi = 0; mi < 2; mi++)
#pragma unroll
                for (int ni = 0; ni < 2; ni++)
                    acc[mi][ni] = __builtin_amdgcn_mfma_f32_32x32x16_bf16(af[mi], bfr[ni], acc[mi][ni], 0, 0, 0);
        }
        __syncthreads();
        p ^= 1;
    }

    __bf16* Cb = (__bf16*)Cv + (size_t)bz * strideC;
    float* Cf = (float*)Cv + (size_t)bz * strideC;
#pragma unroll
    for (int mi = 0; mi < 2; mi++)
#pragma unroll
        for (int ni = 0; ni < 2; ni++) {
            const int cm = bm + wm + mi * 32;
            const int cn = bn + wn + ni * 32 + lane31;
            const float bv = BIAS ? bias[cn] : 0.0f;
#pragma unroll
            for (int rq = 0; rq < 4; rq++) {
                const int rbase = rq * 8 + 4 * hi;
                if constexpr (CFLOAT) {
#pragma unroll
                    for (int rr = 0; rr < 4; rr++)
                        Cf[(size_t)(cm + rbase + rr) * ldc + cn] = acc[mi][ni][rq * 4 + rr] + bv;
                } else {
#pragma unroll
                    for (int rr = 0; rr < 4; rr++)
                        Cb[(size_t)(cm + rbase + rr) * ldc + cn] = (__bf16)(acc[mi][ni][rq * 4 + rr] + bv);
                }
            }
        }
}

// ---------------------------------------------------------------------------
// Pipeline: pre[cvtF|transpG|b2|cvt-hidden] -> mid[GEMM0 || softmax]
//   -> Yt = Wm·xh^T (pure bf16 NT, transposed-out) -> out = P·Yt^T + b2
// 4 dispatches. Kernel-sum is the optimization target (harness floor ~100us).
// ---------------------------------------------------------------------------
extern "C" void kernel_launch(void* const* d_in, const int* in_sizes, int n_in,
                              void* d_out, int out_size, void* d_ws, size_t ws_size,
                              hipStream_t stream) {
    const float* hidden = (const float*)d_in[0];
    const float* mask   = (const float*)d_in[1];
    const float* R      = (const float*)d_in[2];
    const float* G_w    = (const float*)d_in[3];
    const float* G_b    = (const float*)d_in[4];
    const float* F_w    = (const float*)d_in[5];
    const float* F_b    = (const float*)d_in[6];
    float* out = (float*)d_out;

    constexpr int B = 4, S = 2048, H = 1024;
    char* ws = (char*)d_ws;
    __bf16* probs = (__bf16*)(ws);                   // 32 MB  P[b][q][s]
    __bf16* yt    = (__bf16*)(ws + (32ll << 20));    // 16 MB  Yt[b][h][s]
    __bf16* xh    = (__bf16*)(ws + (48ll << 20));    // 16 MB  xh[s_flat][g]
    __bf16* f_bf  = (__bf16*)(ws + (64ll << 20));    // 2 MB
    __bf16* gt_bf = (__bf16*)(ws + (66ll << 20));    // 2 MB
    __bf16* Wm    = (__bf16*)(ws + (68ll << 20));    // 2 MB
    float*  b2    = (float*)(ws + (70ll << 20));     // 4 KB

    pre_kernel<<<3840, 256, 0, stream>>>(F_w, f_bf, G_w, gt_bf, G_b, F_b, b2,
                                         hidden, xh, H);

    mid_kernel<<<8448, 256, 0, stream>>>(f_bf, gt_bf, Wm, R, mask, probs, H, S);

    // Yt[b][h][s] = sum_g Wm[h][g] * xh[b*S+s][g]
    gemm_wy_kernel<<<512, 256, 0, stream>>>(Wm, xh, yt);

    // out[b][q][o] = sum_s P[b][q][s] * Yt[b][o][s] + b2[o]
    gemm_nt_kernel<true, true><<<512, 256, 0, stream>>>(
        probs, yt, b2, out, S, S, S, H,
        (long)S * S, (long)H * S, (long)S * H);
}